// Round 2
// baseline (289.820 us; speedup 1.0000x reference)
//
#include <hip/hip_runtime.h>

// R8 = RESUBMIT of R7 measurement probe (R7 failed on container acquisition,
// an infra flake -- no compile/verify error). Kernels byte-identical to R6
// (best: 196.1 us). kernel_launch enqueues the (pool, stencil) pair FOUR
// times; repeats are idempotent (pool writes p from inputs only; stencil
// writes out from p only), so correctness is unchanged.
//
// Purpose: rocprof top-5 is saturated by ~59 us harness poison fills
// (fillBufferAligned, 384 MiB each); our kernels never appear, so pool must
// be < 58.4 us, yet total dur = 196 us -- the timed iteration includes the
// fills. Recover the true kernel-pair time P+S via:
//     (dur_R8 - 196.1) / 3 = P + S
// Predictions:
//   P+S ~ 19 us (fills dominate, pool L3-fed)  -> dur ~ 253 us -> ROOFLINE
//   P+S ~ 35 us (pool at HBM roofline)         -> dur ~ 301 us -> ~16us headroom
//   P+S ~ 73 us (prior plateau theory correct) -> dur ~ 415 us -> attack plateau
// Side channel: if P > 59 us, pool_diff_kernel enters rocprof top-5 and its
// FETCH_SIZE tells us whether reads are HBM- or L3-served.

typedef float f4 __attribute__((ext_vector_type(4)));

__global__ __launch_bounds__(256) void pool_diff_kernel(
    const f4* __restrict__ org, const f4* __restrict__ enh,
    float* __restrict__ p) {
  __shared__ float red[128];
  int t = threadIdx.x;
  int s = blockIdx.x;              // strip id = b*128 + py
  int b = s >> 7;
  int py = s & 127;
  int sb = b * 196608 + py * 512;  // float4 units; channel stride 65536

  int j0 = sb + t;
  f4 A0 = __builtin_nontemporal_load(&org[j0]);
  f4 B0 = __builtin_nontemporal_load(&enh[j0]);
  f4 A1 = __builtin_nontemporal_load(&org[j0 + 65536]);
  f4 B1 = __builtin_nontemporal_load(&enh[j0 + 65536]);
  f4 A2 = __builtin_nontemporal_load(&org[j0 + 131072]);
  f4 B2 = __builtin_nontemporal_load(&enh[j0 + 131072]);
  f4 acc = (A0 - B0) + (A1 - B1) + (A2 - B2);

  int j1 = j0 + 256;
  f4 C0 = __builtin_nontemporal_load(&org[j1]);
  f4 D0 = __builtin_nontemporal_load(&enh[j1]);
  f4 C1 = __builtin_nontemporal_load(&org[j1 + 65536]);
  f4 D1 = __builtin_nontemporal_load(&enh[j1 + 65536]);
  f4 C2 = __builtin_nontemporal_load(&org[j1 + 131072]);
  f4 D2 = __builtin_nontemporal_load(&enh[j1 + 131072]);
  acc += (C0 - D0) + (C1 - D1) + (C2 - D2);

  float mine = acc.x + acc.y + acc.z + acc.w;  // (dy pair, px) partial
  if (t >= 128) red[t - 128] = mine;
  __syncthreads();
  if (t < 128) {
    p[b * 16384 + py * 128 + t] = (mine + red[t]) * (1.0f / 48.0f);
  }
}

__global__ __launch_bounds__(256) void espa_stencil_kernel(
    const float* __restrict__ p, float* __restrict__ out) {
  int idx = blockIdx.x * 256 + threadIdx.x;   // = b*16384 + y*128 + x
  int x = idx & 127;
  int y = (idx >> 7) & 127;
  float c = p[idx];
  float l = (x > 0)   ? p[idx - 1]   : 0.f;
  float r = (x < 127) ? p[idx + 1]   : 0.f;
  float u = (y > 0)   ? p[idx - 128] : 0.f;
  float d = (y < 127) ? p[idx + 128] : 0.f;
  float dl = c - l, dr = c - r, du = c - u, dd = c - d;
  out[idx] = dl * dl + dr * dr + du * du + dd * dd;
}

extern "C" void kernel_launch(void* const* d_in, const int* in_sizes, int n_in,
                              void* d_out, int out_size, void* d_ws, size_t ws_size,
                              hipStream_t stream) {
  const f4* org = (const f4*)d_in[0];
  const f4* enh = (const f4*)d_in[1];
  float* p   = (float*)d_ws;       // 32*128*128 floats = 2 MB scratch
  float* out = (float*)d_out;      // 32*1*128*128 floats

  const int N = 32 * 128 * 128;
  // PROBE: 4x idempotent repeats; (dur - 196.1)/3 = P + S.
  for (int rep = 0; rep < 4; ++rep) {
    pool_diff_kernel<<<4096, 256, 0, stream>>>(org, enh, p);
    espa_stencil_kernel<<<N / 256, 256, 0, stream>>>(p, out);
  }
}

// Round 3
// 195.749 us; speedup vs baseline: 1.4806x; 1.4806x over previous
//
#include <hip/hip_runtime.h>

// R9 = revert of the R7/R8 measurement probe back to the single-launch R6
// kernel (best: 196.1 us). PROBE CONCLUSION (R8): 4x-repeat arithmetic gives
//     P+S = (289.8 - 196.1)/3 = 31.2 us  per (pool + stencil) pair,
// vs an HBM-roofline floor of ~30-33 us for the mandatory 201 MB input read
// + 4 MB p/out traffic. The kernel pair runs at ~97-104% of achievable HBM
// BW. The remaining ~165 us of the 196 us total is harness poison-fill
// (fillBufferAligned, 3x ~59us @ 85% HBM peak) -- not addressable from
// kernel_launch. The prior session's "2.86 TB/s demand plateau" attributed
// fill time to the kernel; it does not exist.
//
// Kernel structure (unchanged from R6):
//  - pool_diff_kernel: one 256-thread block per (batch, pooled-row) strip.
//    Each lane reads 6 float4s per dy-half (3 channels x org/enh), forming
//    channel-mean row differences; pairwise lane reduction via 128-float LDS
//    combines the two dy halves; writes pooled difference p (cross-channel
//    mean * 1/48 folds avgpool4 + channel mean into one constant).
//  - espa_stencil_kernel: 4-neighbor difference-of-p squared sum -> E.
//    (d_dir(org_pool) - d_dir(enh_pool) = d_dir(p) by linearity of the
//    directional stencils.)

typedef float f4 __attribute__((ext_vector_type(4)));

__global__ __launch_bounds__(256) void pool_diff_kernel(
    const f4* __restrict__ org, const f4* __restrict__ enh,
    float* __restrict__ p) {
  __shared__ float red[128];
  int t = threadIdx.x;
  int s = blockIdx.x;              // strip id = b*128 + py
  int b = s >> 7;
  int py = s & 127;
  int sb = b * 196608 + py * 512;  // float4 units; channel stride 65536

  int j0 = sb + t;
  f4 A0 = __builtin_nontemporal_load(&org[j0]);
  f4 B0 = __builtin_nontemporal_load(&enh[j0]);
  f4 A1 = __builtin_nontemporal_load(&org[j0 + 65536]);
  f4 B1 = __builtin_nontemporal_load(&enh[j0 + 65536]);
  f4 A2 = __builtin_nontemporal_load(&org[j0 + 131072]);
  f4 B2 = __builtin_nontemporal_load(&enh[j0 + 131072]);
  f4 acc = (A0 - B0) + (A1 - B1) + (A2 - B2);

  int j1 = j0 + 256;
  f4 C0 = __builtin_nontemporal_load(&org[j1]);
  f4 D0 = __builtin_nontemporal_load(&enh[j1]);
  f4 C1 = __builtin_nontemporal_load(&org[j1 + 65536]);
  f4 D1 = __builtin_nontemporal_load(&enh[j1 + 65536]);
  f4 C2 = __builtin_nontemporal_load(&org[j1 + 131072]);
  f4 D2 = __builtin_nontemporal_load(&enh[j1 + 131072]);
  acc += (C0 - D0) + (C1 - D1) + (C2 - D2);

  float mine = acc.x + acc.y + acc.z + acc.w;  // (dy pair, px) partial
  if (t >= 128) red[t - 128] = mine;
  __syncthreads();
  if (t < 128) {
    p[b * 16384 + py * 128 + t] = (mine + red[t]) * (1.0f / 48.0f);
  }
}

__global__ __launch_bounds__(256) void espa_stencil_kernel(
    const float* __restrict__ p, float* __restrict__ out) {
  int idx = blockIdx.x * 256 + threadIdx.x;   // = b*16384 + y*128 + x
  int x = idx & 127;
  int y = (idx >> 7) & 127;
  float c = p[idx];
  float l = (x > 0)   ? p[idx - 1]   : 0.f;
  float r = (x < 127) ? p[idx + 1]   : 0.f;
  float u = (y > 0)   ? p[idx - 128] : 0.f;
  float d = (y < 127) ? p[idx + 128] : 0.f;
  float dl = c - l, dr = c - r, du = c - u, dd = c - d;
  out[idx] = dl * dl + dr * dr + du * du + dd * dd;
}

extern "C" void kernel_launch(void* const* d_in, const int* in_sizes, int n_in,
                              void* d_out, int out_size, void* d_ws, size_t ws_size,
                              hipStream_t stream) {
  const f4* org = (const f4*)d_in[0];
  const f4* enh = (const f4*)d_in[1];
  float* p   = (float*)d_ws;       // 32*128*128 floats = 2 MB scratch
  float* out = (float*)d_out;      // 32*1*128*128 floats

  pool_diff_kernel<<<4096, 256, 0, stream>>>(org, enh, p);  // one block per (b,py)
  const int N = 32 * 128 * 128;
  espa_stencil_kernel<<<N / 256, 256, 0, stream>>>(p, out);
}